// Round 1
// baseline (16129.993 us; speedup 1.0000x reference)
//
#include <hip/hip_runtime.h>

#define NN 8192      // nodes
#define NE 262144    // edges per support
#define BD 512       // batch*d_in feature rows
#define DE 64        // embedding dim

// ---------------- transpose: Y0[n][f] = X[f][n]; Ysum = -Y0 ----------------
__global__ void k_transpose(const float* __restrict__ X, float* __restrict__ Y0,
                            float* __restrict__ Ysum) {
  __shared__ float t[32][33];
  int n0 = blockIdx.x * 32, f0 = blockIdx.y * 32;
  int tx = threadIdx.x, ty = threadIdx.y;
#pragma unroll
  for (int yy = 0; yy < 4; yy++)
    t[ty + 8 * yy][tx] = X[(size_t)(f0 + ty + 8 * yy) * NN + n0 + tx];
  __syncthreads();
#pragma unroll
  for (int yy = 0; yy < 4; yy++) {
    float v = t[tx][ty + 8 * yy];
    size_t o = (size_t)(n0 + ty + 8 * yy) * BD + f0 + tx;
    Y0[o] = v;
    Ysum[o] = -v;
  }
}

// ---------------- stats: ssum[j] += sum_i exp(relu(Z_i . Z_j)) ----------------
__global__ void k_s1(const float* __restrict__ Z, float* __restrict__ ssum) {
  __shared__ float zit[64][68];
  __shared__ float zjt[64][68];
  __shared__ float red[16][68];
  int i0 = blockIdx.x * 64, j0 = blockIdx.y * 64;
  int tid = threadIdx.x;
#pragma unroll
  for (int q = 0; q < 4; q++) {
    int flat = (q * 256 + tid) * 4;
    int r = flat >> 6, c = flat & 63;
    float4 a = *(const float4*)(Z + (size_t)(i0 + r) * DE + c);
    zit[c + 0][r] = a.x; zit[c + 1][r] = a.y; zit[c + 2][r] = a.z; zit[c + 3][r] = a.w;
    float4 b = *(const float4*)(Z + (size_t)(j0 + r) * DE + c);
    zjt[c + 0][r] = b.x; zjt[c + 1][r] = b.y; zjt[c + 2][r] = b.z; zjt[c + 3][r] = b.w;
  }
  __syncthreads();
  int tx = tid & 15, ty = tid >> 4;
  float s[4][4];
#pragma unroll
  for (int a = 0; a < 4; a++)
#pragma unroll
    for (int b = 0; b < 4; b++) s[a][b] = 0.f;
#pragma unroll 8
  for (int k = 0; k < 64; k++) {
    float4 a = *(const float4*)&zit[k][ty * 4];
    float4 b = *(const float4*)&zjt[k][tx * 4];
    float av[4] = {a.x, a.y, a.z, a.w}, bv[4] = {b.x, b.y, b.z, b.w};
#pragma unroll
    for (int ii = 0; ii < 4; ii++)
#pragma unroll
      for (int jj = 0; jj < 4; jj++) s[ii][jj] += av[ii] * bv[jj];
  }
  float cs[4];
#pragma unroll
  for (int jj = 0; jj < 4; jj++) {
    float c = 0.f;
#pragma unroll
    for (int ii = 0; ii < 4; ii++)
      c += __expf(fminf(fmaxf(s[ii][jj], 0.f), 80.f));
    cs[jj] = c;
  }
#pragma unroll
  for (int jj = 0; jj < 4; jj++) red[ty][tx * 4 + jj] = cs[jj];
  __syncthreads();
  if (tid < 64) {
    float acc = 0.f;
#pragma unroll
    for (int g = 0; g < 16; g++) acc += red[g][tid];
    atomicAdd(ssum + j0 + tid, acc);
  }
}

__global__ void k_inv(const float* __restrict__ ssum, float* __restrict__ invs) {
  int i = blockIdx.x * 256 + threadIdx.x;
  invs[i] = 1.0f / ssum[i];
}

// ---------------- SpMM: dst[row] += scale*w*src[col]  (one wave per edge) ----------------
__global__ void k_spmm(const int* __restrict__ rows, const int* __restrict__ cols,
                       const float* __restrict__ w, const float* __restrict__ src,
                       float* __restrict__ dst, float scale) {
  int t = blockIdx.x * 256 + threadIdx.x;
  int e = t >> 6, lane = t & 63;
  int r = rows[e], c = cols[e];
  float wt = w[e] * scale;
  const float4* s4 = (const float4*)(src + (size_t)c * BD) + lane * 2;
  float4 v0 = s4[0], v1 = s4[1];
  float* d = dst + (size_t)r * BD + lane * 8;
  atomicAdd(d + 0, wt * v0.x); atomicAdd(d + 1, wt * v0.y);
  atomicAdd(d + 2, wt * v0.z); atomicAdd(d + 3, wt * v0.w);
  atomicAdd(d + 4, wt * v1.x); atomicAdd(d + 5, wt * v1.y);
  atomicAdd(d + 6, wt * v1.z); atomicAdd(d + 7, wt * v1.w);
}

__global__ void k_add(float* __restrict__ dst, const float* __restrict__ a) {
  int t = blockIdx.x * 256 + threadIdx.x;
  float4 u = ((const float4*)a)[t];
  float4 d = ((float4*)dst)[t];
  d.x += u.x; d.y += u.y; d.z += u.z; d.w += u.w;
  ((float4*)dst)[t] = d;
}

// ---------------- fused adaptive-adjacency GEMM ----------------
// Ysum[i, f] += sum_j exp(relu(Z_i.Z_j))*invs[j] * Y0[j, f]
// BM=32 (i), BN=256 (f), JSTEP=128, phase-B sub-chunks of 16 j.
__global__ __launch_bounds__(256) void k2(const float* __restrict__ Z,
                                          const float* __restrict__ Y0,
                                          const float* __restrict__ invs,
                                          float* __restrict__ Ysum) {
  __shared__ float zit[64][36];        // Z[i-tile] transposed [k][i]
  __shared__ float zjg[64 * 132];      // Zjt [k][128+4]  ALIASED as Gt [128][36]
  __shared__ float y0t[16][260];       // Y0 sub-tile [j][f]
  int i0 = blockIdx.x * 32;
  int f0 = blockIdx.y * 256;
  int tid = threadIdx.x;
  int tx = tid & 31, ty = tid >> 5;

#pragma unroll
  for (int q = 0; q < 2; q++) {
    int flat = (q * 256 + tid) * 4;
    int r = flat >> 6, c = flat & 63;
    float4 a = *(const float4*)(Z + (size_t)(i0 + r) * DE + c);
    zit[c + 0][r] = a.x; zit[c + 1][r] = a.y; zit[c + 2][r] = a.z; zit[c + 3][r] = a.w;
  }

  float acc[4][2][4];
#pragma unroll
  for (int ii = 0; ii < 4; ii++)
#pragma unroll
    for (int q = 0; q < 2; q++)
#pragma unroll
      for (int ff = 0; ff < 4; ff++) acc[ii][q][ff] = 0.f;

  for (int js = 0; js < 64; js++) {
    int j0 = js * 128;
    __syncthreads();  // zit ready (js=0); zjg/Gt readers of js-1 done
#pragma unroll
    for (int q = 0; q < 8; q++) {
      int flat = (q * 256 + tid) * 4;
      int r = flat >> 6, c = flat & 63;
      float4 a = *(const float4*)(Z + (size_t)(j0 + r) * DE + c);
      zjg[(c + 0) * 132 + r] = a.x; zjg[(c + 1) * 132 + r] = a.y;
      zjg[(c + 2) * 132 + r] = a.z; zjg[(c + 3) * 132 + r] = a.w;
    }
    __syncthreads();
    // ---- phase A: S[32 i][128 j] ----
    float sa[4][4];
#pragma unroll
    for (int ii = 0; ii < 4; ii++)
#pragma unroll
      for (int jj = 0; jj < 4; jj++) sa[ii][jj] = 0.f;
#pragma unroll 8
    for (int k = 0; k < 64; k++) {
      float4 a = *(const float4*)&zit[k][ty * 4];
      float4 b = *(const float4*)&zjg[k * 132 + tx * 4];
      float av[4] = {a.x, a.y, a.z, a.w}, bv[4] = {b.x, b.y, b.z, b.w};
#pragma unroll
      for (int ii = 0; ii < 4; ii++)
#pragma unroll
        for (int jj = 0; jj < 4; jj++) sa[ii][jj] += av[ii] * bv[jj];
    }
    float4 giv = *(const float4*)(invs + j0 + tx * 4);
    float ivv[4] = {giv.x, giv.y, giv.z, giv.w};
    __syncthreads();  // all Zjt reads done before Gt overwrites the alias
#pragma unroll
    for (int jj = 0; jj < 4; jj++) {
      float4 g;
      g.x = __expf(fminf(fmaxf(sa[0][jj], 0.f), 80.f)) * ivv[jj];
      g.y = __expf(fminf(fmaxf(sa[1][jj], 0.f), 80.f)) * ivv[jj];
      g.z = __expf(fminf(fmaxf(sa[2][jj], 0.f), 80.f)) * ivv[jj];
      g.w = __expf(fminf(fmaxf(sa[3][jj], 0.f), 80.f)) * ivv[jj];
      *(float4*)&zjg[(tx * 4 + jj) * 36 + ty * 4] = g;  // Gt[j][i]
    }
    __syncthreads();
    // ---- phase B ----
#pragma unroll 1
    for (int sub = 0; sub < 8; sub++) {
#pragma unroll
      for (int q = 0; q < 4; q++) {
        int flat = (q * 256 + tid) * 4;
        int rr = flat >> 8, cc = flat & 255;
        *(float4*)&y0t[rr][cc] =
            *(const float4*)(Y0 + (size_t)(j0 + sub * 16 + rr) * BD + f0 + cc);
      }
      __syncthreads();
#pragma unroll
      for (int kk = 0; kk < 16; kk++) {
        float4 a = *(const float4*)&zjg[(sub * 16 + kk) * 36 + ty * 4];
        float4 b0 = *(const float4*)&y0t[kk][tx * 4];
        float4 b1 = *(const float4*)&y0t[kk][tx * 4 + 128];
        float av[4] = {a.x, a.y, a.z, a.w};
        float b0v[4] = {b0.x, b0.y, b0.z, b0.w};
        float b1v[4] = {b1.x, b1.y, b1.z, b1.w};
#pragma unroll
        for (int ii = 0; ii < 4; ii++)
#pragma unroll
          for (int ff = 0; ff < 4; ff++) {
            acc[ii][0][ff] += av[ii] * b0v[ff];
            acc[ii][1][ff] += av[ii] * b1v[ff];
          }
      }
      __syncthreads();
    }
  }
#pragma unroll
  for (int ii = 0; ii < 4; ii++)
#pragma unroll
    for (int q = 0; q < 2; q++) {
      size_t o = (size_t)(i0 + ty * 4 + ii) * BD + f0 + tx * 4 + q * 128;
      float4 d = *(float4*)(Ysum + o);
      d.x += acc[ii][q][0]; d.y += acc[ii][q][1];
      d.z += acc[ii][q][2]; d.w += acc[ii][q][3];
      *(float4*)(Ysum + o) = d;
    }
}

// ---------------- out[b,n,o] = sum_d Ysum[n, b*32+d] * W[d,o] ----------------
__global__ void k3(const float* __restrict__ Ysum, const float* __restrict__ W,
                   float* __restrict__ out) {
  __shared__ float yt[32][68];  // [d][n]
  __shared__ float wt[32][68];  // [d][o]
  int n0 = blockIdx.x * 64;
  int b = blockIdx.y;
  int tid = threadIdx.x;
#pragma unroll
  for (int q = 0; q < 2; q++) {
    int flat = (q * 256 + tid) * 4;
    int r = flat >> 5, c = flat & 31;  // n-row, d-col
    float4 a = *(const float4*)(Ysum + (size_t)(n0 + r) * BD + b * 32 + c);
    yt[c + 0][r] = a.x; yt[c + 1][r] = a.y; yt[c + 2][r] = a.z; yt[c + 3][r] = a.w;
    int flat2 = (q * 256 + tid) * 4;
    int rd = flat2 >> 6, co = flat2 & 63;
    *(float4*)&wt[rd][co] = *(const float4*)(W + rd * 64 + co);
  }
  __syncthreads();
  int tx = tid & 15, ty = tid >> 4;
  float acc[4][4];
#pragma unroll
  for (int a = 0; a < 4; a++)
#pragma unroll
    for (int bq = 0; bq < 4; bq++) acc[a][bq] = 0.f;
#pragma unroll
  for (int d = 0; d < 32; d++) {
    float4 a = *(const float4*)&yt[d][ty * 4];
    float4 w4 = *(const float4*)&wt[d][tx * 4];
    float av[4] = {a.x, a.y, a.z, a.w}, wv[4] = {w4.x, w4.y, w4.z, w4.w};
#pragma unroll
    for (int nn = 0; nn < 4; nn++)
#pragma unroll
      for (int oo = 0; oo < 4; oo++) acc[nn][oo] += av[nn] * wv[oo];
  }
#pragma unroll
  for (int nn = 0; nn < 4; nn++) {
    float4 v = {acc[nn][0], acc[nn][1], acc[nn][2], acc[nn][3]};
    *(float4*)(out + (size_t)b * NN * 64 + (size_t)(n0 + ty * 4 + nn) * 64 + tx * 4) = v;
  }
}

extern "C" void kernel_launch(void* const* d_in, const int* in_sizes, int n_in,
                              void* d_out, int out_size, void* d_ws, size_t ws_size,
                              hipStream_t stream) {
  const int* erow = (const int*)d_in[0];
  const int* ecol = (const int*)d_in[1];
  const float* ew = (const float*)d_in[2];
  const float* X = (const float*)d_in[3];
  const float* Z = (const float*)d_in[4];
  const float* W = (const float*)d_in[5];
  float* out = (float*)d_out;

  float* Y0 = (float*)d_ws;                     // [NN][BD]
  float* Ysum = Y0 + (size_t)NN * BD;           // [NN][BD]
  float* Y1 = Ysum + (size_t)NN * BD;           // [NN][BD]
  float* ssum = Y1 + (size_t)NN * BD;           // [NN]
  float* invs = ssum + NN;                      // [NN]

  k_transpose<<<dim3(NN / 32, BD / 32), dim3(32, 8), 0, stream>>>(X, Y0, Ysum);
  hipMemsetAsync(ssum, 0, NN * sizeof(float), stream);
  k_s1<<<dim3(128, 128), 256, 0, stream>>>(Z, ssum);
  k_inv<<<NN / 256, 256, 0, stream>>>(ssum, invs);
  for (int k = 0; k < 2; k++) {
    hipMemsetAsync(Y1, 0, (size_t)NN * BD * sizeof(float), stream);
    k_spmm<<<NE * 64 / 256, 256, 0, stream>>>(erow + (size_t)k * NE, ecol + (size_t)k * NE,
                                              ew + (size_t)k * NE, Y0, Y1, 1.0f);
    k_add<<<NN * BD / 4 / 256, 256, 0, stream>>>(Ysum, Y1);
    k_spmm<<<NE * 64 / 256, 256, 0, stream>>>(erow + (size_t)k * NE, ecol + (size_t)k * NE,
                                              ew + (size_t)k * NE, Y1, Ysum, 2.0f);
  }
  k2<<<dim3(NN / 32, 2), 256, 0, stream>>>(Z, Y0, invs, Ysum);
  k3<<<dim3(NN / 64, 16), 256, 0, stream>>>(Ysum, W, out);
}

// Round 2
// 1974.180 us; speedup vs baseline: 8.1705x; 8.1705x over previous
//
#include <hip/hip_runtime.h>

#define NN 8192      // nodes
#define NE 262144    // edges per support (2^18)
#define BD 512       // batch*d_in feature rows
#define DE 64        // embedding dim

// ---------------- transpose: Y0[n][f] = X[f][n]; Ysum = -Y0 ----------------
__global__ void k_transpose(const float* __restrict__ X, float* __restrict__ Y0,
                            float* __restrict__ Ysum) {
  __shared__ float t[32][33];
  int n0 = blockIdx.x * 32, f0 = blockIdx.y * 32;
  int tx = threadIdx.x, ty = threadIdx.y;
#pragma unroll
  for (int yy = 0; yy < 4; yy++)
    t[ty + 8 * yy][tx] = X[(size_t)(f0 + ty + 8 * yy) * NN + n0 + tx];
  __syncthreads();
#pragma unroll
  for (int yy = 0; yy < 4; yy++) {
    float v = t[tx][ty + 8 * yy];
    size_t o = (size_t)(n0 + ty + 8 * yy) * BD + f0 + tx;
    Y0[o] = v;
    Ysum[o] = -v;
  }
}

// ---------------- stats: ssum[j] += sum_i exp(relu(Z_i . Z_j)) ----------------
__global__ void k_s1(const float* __restrict__ Z, float* __restrict__ ssum) {
  __shared__ float zit[64][68];
  __shared__ float zjt[64][68];
  __shared__ float red[16][68];
  int i0 = blockIdx.x * 64, j0 = blockIdx.y * 64;
  int tid = threadIdx.x;
#pragma unroll
  for (int q = 0; q < 4; q++) {
    int flat = (q * 256 + tid) * 4;
    int r = flat >> 6, c = flat & 63;
    float4 a = *(const float4*)(Z + (size_t)(i0 + r) * DE + c);
    zit[c + 0][r] = a.x; zit[c + 1][r] = a.y; zit[c + 2][r] = a.z; zit[c + 3][r] = a.w;
    float4 b = *(const float4*)(Z + (size_t)(j0 + r) * DE + c);
    zjt[c + 0][r] = b.x; zjt[c + 1][r] = b.y; zjt[c + 2][r] = b.z; zjt[c + 3][r] = b.w;
  }
  __syncthreads();
  int tx = tid & 15, ty = tid >> 4;
  float s[4][4];
#pragma unroll
  for (int a = 0; a < 4; a++)
#pragma unroll
    for (int b = 0; b < 4; b++) s[a][b] = 0.f;
#pragma unroll 8
  for (int k = 0; k < 64; k++) {
    float4 a = *(const float4*)&zit[k][ty * 4];
    float4 b = *(const float4*)&zjt[k][tx * 4];
    float av[4] = {a.x, a.y, a.z, a.w}, bv[4] = {b.x, b.y, b.z, b.w};
#pragma unroll
    for (int ii = 0; ii < 4; ii++)
#pragma unroll
      for (int jj = 0; jj < 4; jj++) s[ii][jj] += av[ii] * bv[jj];
  }
  float cs[4];
#pragma unroll
  for (int jj = 0; jj < 4; jj++) {
    float c = 0.f;
#pragma unroll
    for (int ii = 0; ii < 4; ii++)
      c += __expf(fminf(fmaxf(s[ii][jj], 0.f), 80.f));
    cs[jj] = c;
  }
#pragma unroll
  for (int jj = 0; jj < 4; jj++) red[ty][tx * 4 + jj] = cs[jj];
  __syncthreads();
  if (tid < 64) {
    float acc = 0.f;
#pragma unroll
    for (int g = 0; g < 16; g++) acc += red[g][tid];
    atomicAdd(ssum + j0 + tid, acc);
  }
}

__global__ void k_inv(const float* __restrict__ ssum, float* __restrict__ invs) {
  int i = blockIdx.x * 256 + threadIdx.x;
  invs[i] = 1.0f / ssum[i];
}

// ---------------- CSR build ----------------
__global__ void k_hist(const int* __restrict__ erow, int* __restrict__ cnt) {
  int t = blockIdx.x * 256 + threadIdx.x;   // t over 2*NE
  int k = t >> 18;                          // NE = 2^18
  atomicAdd(cnt + k * NN + erow[t], 1);
}

// one block per support: exclusive scan of 8192 counts -> rowptr, fill
__global__ __launch_bounds__(256) void k_scan(const int* __restrict__ cnt,
                                              int* __restrict__ rowptr,
                                              int* __restrict__ fill) {
  int k = blockIdx.x;
  const int* c = cnt + k * NN;
  int* rp = rowptr + k * (NN + 1);
  int* fl = fill + k * NN;
  __shared__ int part[256];
  int t = threadIdx.x;
  int local[32];
  int s = 0;
#pragma unroll
  for (int i = 0; i < 32; i++) { local[i] = c[t * 32 + i]; s += local[i]; }
  part[t] = s;
  __syncthreads();
  for (int off = 1; off < 256; off <<= 1) {
    int v = (t >= off) ? part[t - off] : 0;
    __syncthreads();
    part[t] += v;
    __syncthreads();
  }
  int run = (t == 0) ? 0 : part[t - 1];
#pragma unroll
  for (int i = 0; i < 32; i++) {
    rp[t * 32 + i] = run;
    fl[t * 32 + i] = run;
    run += local[i];
  }
  if (t == 255) rp[NN] = run;
}

__global__ void k_scatter(const int* __restrict__ erow, const int* __restrict__ ecol,
                          const float* __restrict__ ew, int* __restrict__ fill,
                          int* __restrict__ ecol_s, float* __restrict__ ew_s) {
  int t = blockIdx.x * 256 + threadIdx.x;   // t over 2*NE
  int k = t >> 18;
  int r = erow[t];
  int pos = atomicAdd(fill + k * NN + r, 1);
  ecol_s[(size_t)k * NE + pos] = ecol[t];
  ew_s[(size_t)k * NE + pos] = ew[t];
}

// ---------------- CSR SpMM: one wave per row, no atomics ----------------
// extra==null:  dst[row] = sum_e w*src[col]
// extra!=null:  dst[row] += scale*sum_e w*src[col] + extra[row]
__global__ __launch_bounds__(256) void k_csr(const int* __restrict__ rowptr,
                                             const int* __restrict__ cols,
                                             const float* __restrict__ w,
                                             const float* __restrict__ src,
                                             float* __restrict__ dst,
                                             const float* __restrict__ extra,
                                             float scale) {
  int wid = threadIdx.x >> 6;
  int lane = threadIdx.x & 63;
  int row = blockIdx.x * 4 + wid;
  int start = rowptr[row], end = rowptr[row + 1];
  float a0x = 0.f, a0y = 0.f, a0z = 0.f, a0w = 0.f;
  float a1x = 0.f, a1y = 0.f, a1z = 0.f, a1w = 0.f;
  for (int e = start; e < end; e++) {
    int c = __builtin_amdgcn_readfirstlane(cols[e]);
    float wv = w[e];
    const float4* s = (const float4*)(src + (size_t)c * BD);
    float4 v0 = s[lane], v1 = s[lane + 64];
    a0x += wv * v0.x; a0y += wv * v0.y; a0z += wv * v0.z; a0w += wv * v0.w;
    a1x += wv * v1.x; a1y += wv * v1.y; a1z += wv * v1.z; a1w += wv * v1.w;
  }
  float4* d = (float4*)(dst + (size_t)row * BD);
  if (extra) {
    const float4* ex = (const float4*)(extra + (size_t)row * BD);
    float4 e0 = ex[lane], e1 = ex[lane + 64];
    float4 d0 = d[lane], d1 = d[lane + 64];
    d0.x += scale * a0x + e0.x; d0.y += scale * a0y + e0.y;
    d0.z += scale * a0z + e0.z; d0.w += scale * a0w + e0.w;
    d1.x += scale * a1x + e1.x; d1.y += scale * a1y + e1.y;
    d1.z += scale * a1z + e1.z; d1.w += scale * a1w + e1.w;
    d[lane] = d0; d[lane + 64] = d1;
  } else {
    float4 d0 = {a0x, a0y, a0z, a0w};
    float4 d1 = {a1x, a1y, a1z, a1w};
    d[lane] = d0; d[lane + 64] = d1;
  }
}

// ---------------- fused adaptive-adjacency GEMM ----------------
// Ysum[i, f] += sum_j exp(relu(Z_i.Z_j))*invs[j] * Y0[j, f]
__global__ __launch_bounds__(256) void k2(const float* __restrict__ Z,
                                          const float* __restrict__ Y0,
                                          const float* __restrict__ invs,
                                          float* __restrict__ Ysum) {
  __shared__ float zit[64][36];        // Z[i-tile] transposed [k][i]
  __shared__ float zjg[64 * 132];      // Zjt [k][128+4]  ALIASED as Gt [128][36]
  __shared__ float y0t[16][260];       // Y0 sub-tile [j][f]
  int i0 = blockIdx.x * 32;
  int f0 = blockIdx.y * 256;
  int tid = threadIdx.x;
  int tx = tid & 31, ty = tid >> 5;

#pragma unroll
  for (int q = 0; q < 2; q++) {
    int flat = (q * 256 + tid) * 4;
    int r = flat >> 6, c = flat & 63;
    float4 a = *(const float4*)(Z + (size_t)(i0 + r) * DE + c);
    zit[c + 0][r] = a.x; zit[c + 1][r] = a.y; zit[c + 2][r] = a.z; zit[c + 3][r] = a.w;
  }

  float acc[4][2][4];
#pragma unroll
  for (int ii = 0; ii < 4; ii++)
#pragma unroll
    for (int q = 0; q < 2; q++)
#pragma unroll
      for (int ff = 0; ff < 4; ff++) acc[ii][q][ff] = 0.f;

  for (int js = 0; js < 64; js++) {
    int j0 = js * 128;
    __syncthreads();
#pragma unroll
    for (int q = 0; q < 8; q++) {
      int flat = (q * 256 + tid) * 4;
      int r = flat >> 6, c = flat & 63;
      float4 a = *(const float4*)(Z + (size_t)(j0 + r) * DE + c);
      zjg[(c + 0) * 132 + r] = a.x; zjg[(c + 1) * 132 + r] = a.y;
      zjg[(c + 2) * 132 + r] = a.z; zjg[(c + 3) * 132 + r] = a.w;
    }
    __syncthreads();
    float sa[4][4];
#pragma unroll
    for (int ii = 0; ii < 4; ii++)
#pragma unroll
      for (int jj = 0; jj < 4; jj++) sa[ii][jj] = 0.f;
#pragma unroll 8
    for (int k = 0; k < 64; k++) {
      float4 a = *(const float4*)&zit[k][ty * 4];
      float4 b = *(const float4*)&zjg[k * 132 + tx * 4];
      float av[4] = {a.x, a.y, a.z, a.w}, bv[4] = {b.x, b.y, b.z, b.w};
#pragma unroll
      for (int ii = 0; ii < 4; ii++)
#pragma unroll
        for (int jj = 0; jj < 4; jj++) sa[ii][jj] += av[ii] * bv[jj];
    }
    float4 giv = *(const float4*)(invs + j0 + tx * 4);
    float ivv[4] = {giv.x, giv.y, giv.z, giv.w};
    __syncthreads();
#pragma unroll
    for (int jj = 0; jj < 4; jj++) {
      float4 g;
      g.x = __expf(fminf(fmaxf(sa[0][jj], 0.f), 80.f)) * ivv[jj];
      g.y = __expf(fminf(fmaxf(sa[1][jj], 0.f), 80.f)) * ivv[jj];
      g.z = __expf(fminf(fmaxf(sa[2][jj], 0.f), 80.f)) * ivv[jj];
      g.w = __expf(fminf(fmaxf(sa[3][jj], 0.f), 80.f)) * ivv[jj];
      *(float4*)&zjg[(tx * 4 + jj) * 36 + ty * 4] = g;  // Gt[j][i]
    }
    __syncthreads();
#pragma unroll 1
    for (int sub = 0; sub < 8; sub++) {
#pragma unroll
      for (int q = 0; q < 4; q++) {
        int flat = (q * 256 + tid) * 4;
        int rr = flat >> 8, cc = flat & 255;
        *(float4*)&y0t[rr][cc] =
            *(const float4*)(Y0 + (size_t)(j0 + sub * 16 + rr) * BD + f0 + cc);
      }
      __syncthreads();
#pragma unroll
      for (int kk = 0; kk < 16; kk++) {
        float4 a = *(const float4*)&zjg[(sub * 16 + kk) * 36 + ty * 4];
        float4 b0 = *(const float4*)&y0t[kk][tx * 4];
        float4 b1 = *(const float4*)&y0t[kk][tx * 4 + 128];
        float av[4] = {a.x, a.y, a.z, a.w};
        float b0v[4] = {b0.x, b0.y, b0.z, b0.w};
        float b1v[4] = {b1.x, b1.y, b1.z, b1.w};
#pragma unroll
        for (int ii = 0; ii < 4; ii++)
#pragma unroll
          for (int ff = 0; ff < 4; ff++) {
            acc[ii][0][ff] += av[ii] * b0v[ff];
            acc[ii][1][ff] += av[ii] * b1v[ff];
          }
      }
      __syncthreads();
    }
  }
#pragma unroll
  for (int ii = 0; ii < 4; ii++)
#pragma unroll
    for (int q = 0; q < 2; q++) {
      size_t o = (size_t)(i0 + ty * 4 + ii) * BD + f0 + tx * 4 + q * 128;
      float4 d = *(float4*)(Ysum + o);
      d.x += acc[ii][q][0]; d.y += acc[ii][q][1];
      d.z += acc[ii][q][2]; d.w += acc[ii][q][3];
      *(float4*)(Ysum + o) = d;
    }
}

// ---------------- out[b,n,o] = sum_d Ysum[n, b*32+d] * W[d,o] ----------------
__global__ void k3(const float* __restrict__ Ysum, const float* __restrict__ W,
                   float* __restrict__ out) {
  __shared__ float yt[32][68];  // [d][n]
  __shared__ float wt[32][68];  // [d][o]
  int n0 = blockIdx.x * 64;
  int b = blockIdx.y;
  int tid = threadIdx.x;
#pragma unroll
  for (int q = 0; q < 2; q++) {
    int flat = (q * 256 + tid) * 4;
    int r = flat >> 5, c = flat & 31;
    float4 a = *(const float4*)(Ysum + (size_t)(n0 + r) * BD + b * 32 + c);
    yt[c + 0][r] = a.x; yt[c + 1][r] = a.y; yt[c + 2][r] = a.z; yt[c + 3][r] = a.w;
    int flat2 = (q * 256 + tid) * 4;
    int rd = flat2 >> 6, co = flat2 & 63;
    *(float4*)&wt[rd][co] = *(const float4*)(W + rd * 64 + co);
  }
  __syncthreads();
  int tx = tid & 15, ty = tid >> 4;
  float acc[4][4];
#pragma unroll
  for (int a = 0; a < 4; a++)
#pragma unroll
    for (int bq = 0; bq < 4; bq++) acc[a][bq] = 0.f;
#pragma unroll
  for (int d = 0; d < 32; d++) {
    float4 a = *(const float4*)&yt[d][ty * 4];
    float4 w4 = *(const float4*)&wt[d][tx * 4];
    float av[4] = {a.x, a.y, a.z, a.w}, wv[4] = {w4.x, w4.y, w4.z, w4.w};
#pragma unroll
    for (int nn = 0; nn < 4; nn++)
#pragma unroll
      for (int oo = 0; oo < 4; oo++) acc[nn][oo] += av[nn] * wv[oo];
  }
#pragma unroll
  for (int nn = 0; nn < 4; nn++) {
    float4 v = {acc[nn][0], acc[nn][1], acc[nn][2], acc[nn][3]};
    *(float4*)(out + (size_t)b * NN * 64 + (size_t)(n0 + ty * 4 + nn) * 64 + tx * 4) = v;
  }
}

extern "C" void kernel_launch(void* const* d_in, const int* in_sizes, int n_in,
                              void* d_out, int out_size, void* d_ws, size_t ws_size,
                              hipStream_t stream) {
  const int* erow = (const int*)d_in[0];
  const int* ecol = (const int*)d_in[1];
  const float* ew = (const float*)d_in[2];
  const float* X = (const float*)d_in[3];
  const float* Z = (const float*)d_in[4];
  const float* W = (const float*)d_in[5];
  float* out = (float*)d_out;

  float* Y0 = (float*)d_ws;                     // [NN][BD]
  float* Ysum = Y0 + (size_t)NN * BD;           // [NN][BD]
  float* Y1 = Ysum + (size_t)NN * BD;           // [NN][BD]
  float* ssum = Y1 + (size_t)NN * BD;           // [NN]
  float* invs = ssum + NN;                      // [NN]
  int* cnt = (int*)(invs + NN);                 // [2][NN]
  int* rowptr = cnt + 2 * NN;                   // [2][NN+1]
  int* fill = rowptr + 2 * (NN + 1);            // [2][NN]
  int* ecol_s = fill + 2 * NN;                  // [2][NE]
  float* ew_s = (float*)(ecol_s + 2 * NE);      // [2][NE]

  k_transpose<<<dim3(NN / 32, BD / 32), dim3(32, 8), 0, stream>>>(X, Y0, Ysum);
  hipMemsetAsync(ssum, 0, NN * sizeof(float), stream);
  hipMemsetAsync(cnt, 0, 2 * NN * sizeof(int), stream);
  k_hist<<<2 * NE / 256, 256, 0, stream>>>(erow, cnt);
  k_scan<<<2, 256, 0, stream>>>(cnt, rowptr, fill);
  k_scatter<<<2 * NE / 256, 256, 0, stream>>>(erow, ecol, ew, fill, ecol_s, ew_s);
  k_s1<<<dim3(128, 128), 256, 0, stream>>>(Z, ssum);
  k_inv<<<NN / 256, 256, 0, stream>>>(ssum, invs);
  for (int k = 0; k < 2; k++) {
    const int* rp = rowptr + k * (NN + 1);
    const int* cs = ecol_s + (size_t)k * NE;
    const float* ws = ew_s + (size_t)k * NE;
    k_csr<<<NN / 4, 256, 0, stream>>>(rp, cs, ws, Y0, Y1, nullptr, 1.0f);
    k_csr<<<NN / 4, 256, 0, stream>>>(rp, cs, ws, Y1, Ysum, Y1, 2.0f);
  }
  k2<<<dim3(NN / 32, 2), 256, 0, stream>>>(Z, Y0, invs, Ysum);
  k3<<<dim3(NN / 64, 16), 256, 0, stream>>>(Ysum, W, out);
}

// Round 3
// 845.729 us; speedup vs baseline: 19.0723x; 2.3343x over previous
//
#include <hip/hip_runtime.h>

#define NN 8192      // nodes
#define NE 262144    // edges per support (2^18)
#define BD 512       // batch*d_in feature rows
#define DE 64        // embedding dim

typedef __attribute__((ext_vector_type(8))) short short8;
typedef __attribute__((ext_vector_type(4))) short short4v;
typedef __attribute__((ext_vector_type(16))) float float16;

#define MFMA(a, b, c) __builtin_amdgcn_mfma_f32_32x32x16_bf16(a, b, c, 0, 0, 0)

static __device__ __forceinline__ unsigned short f2b(float x) {
  unsigned u = __float_as_uint(x);
  return (unsigned short)((u + 0x7fffu + ((u >> 16) & 1u)) >> 16);  // RNE
}
static __device__ __forceinline__ float b2f(unsigned short h) {
  return __uint_as_float(((unsigned)h) << 16);
}

// ---------------- transpose: Y0[n][f] = X[f][n]; Ysum = -Y0 ----------------
__global__ void k_transpose(const float* __restrict__ X, float* __restrict__ Y0,
                            float* __restrict__ Ysum) {
  __shared__ float t[32][33];
  int n0 = blockIdx.x * 32, f0 = blockIdx.y * 32;
  int tx = threadIdx.x, ty = threadIdx.y;
#pragma unroll
  for (int yy = 0; yy < 4; yy++)
    t[ty + 8 * yy][tx] = X[(size_t)(f0 + ty + 8 * yy) * NN + n0 + tx];
  __syncthreads();
#pragma unroll
  for (int yy = 0; yy < 4; yy++) {
    float v = t[tx][ty + 8 * yy];
    size_t o = (size_t)(n0 + ty + 8 * yy) * BD + f0 + tx;
    Y0[o] = v;
    Ysum[o] = -v;
  }
}

// ---------------- cast: Y0bT[f][n] = bf16(X[f][n])  (X already [f][n]) ----------------
__global__ void k_cast(const float* __restrict__ X, unsigned short* __restrict__ Y0bT) {
  size_t t = (size_t)(blockIdx.x * 256 + threadIdx.x) * 8;
  float4 a = *(const float4*)(X + t);
  float4 b = *(const float4*)(X + t + 4);
  short8 v;
  v[0] = (short)f2b(a.x); v[1] = (short)f2b(a.y);
  v[2] = (short)f2b(a.z); v[3] = (short)f2b(a.w);
  v[4] = (short)f2b(b.x); v[5] = (short)f2b(b.y);
  v[6] = (short)f2b(b.z); v[7] = (short)f2b(b.w);
  *(short8*)(Y0bT + t) = v;
}

// ---------------- Z split: Z ~= Zh + Zl (bf16 pair) ----------------
__global__ void k_zsplit(const float* __restrict__ Z, unsigned short* __restrict__ Zh,
                         unsigned short* __restrict__ Zl) {
  size_t t = (size_t)(blockIdx.x * 256 + threadIdx.x) * 4;
  float4 a = *(const float4*)(Z + t);
  float f[4] = {a.x, a.y, a.z, a.w};
  short4v hv, lv;
#pragma unroll
  for (int i = 0; i < 4; i++) {
    unsigned short hh = f2b(f[i]);
    hv[i] = (short)hh;
    lv[i] = (short)f2b(f[i] - b2f(hh));
  }
  *(short4v*)(Zh + t) = hv;
  *(short4v*)(Zl + t) = lv;
}

// ---------------- colsum: ssum[j] = sum_i exp(relu(Z_i . Z_j))  (MFMA) ----------------
__global__ __launch_bounds__(256) void k_colsum(const unsigned short* __restrict__ Zh,
                                                const unsigned short* __restrict__ Zl,
                                                float* __restrict__ ssum) {
  int jt = blockIdx.x;     // 128 j-tiles of 64
  int chunk = blockIdx.y;  // 4 i-chunks of 2048
  int tid = threadIdx.x;
  int w = tid >> 6, lane = tid & 63, li = lane & 31, h = lane >> 5;
  int jb = jt * 64 + (w & 1) * 32 + li;
  short8 bjh[4], bjl[4];
#pragma unroll
  for (int ks = 0; ks < 4; ks++) {
    bjh[ks] = *(const short8*)(Zh + (size_t)jb * DE + ks * 16 + 8 * h);
    bjl[ks] = *(const short8*)(Zl + (size_t)jb * DE + ks * 16 + 8 * h);
  }
  float csum = 0.f;
  for (int it = 0; it < 32; it++) {
    int ib = chunk * 2048 + (w >> 1) * 32 + it * 64 + li;
    short8 aih[4], ail[4];
#pragma unroll
    for (int ks = 0; ks < 4; ks++) {
      aih[ks] = *(const short8*)(Zh + (size_t)ib * DE + ks * 16 + 8 * h);
      ail[ks] = *(const short8*)(Zl + (size_t)ib * DE + ks * 16 + 8 * h);
    }
    float16 s;
#pragma unroll
    for (int r = 0; r < 16; r++) s[r] = 0.f;
#pragma unroll
    for (int ks = 0; ks < 4; ks++) {
      s = MFMA(aih[ks], bjh[ks], s);
      s = MFMA(aih[ks], bjl[ks], s);
      s = MFMA(ail[ks], bjh[ks], s);
    }
#pragma unroll
    for (int r = 0; r < 16; r++)
      csum += __expf(fminf(fmaxf(s[r], 0.f), 80.f));
  }
  csum += __shfl_xor(csum, 32);
  if (lane < 32) atomicAdd(ssum + jb, csum);
}

__global__ void k_inv(const float* __restrict__ ssum, float* __restrict__ invs) {
  int i = blockIdx.x * 256 + threadIdx.x;
  invs[i] = 1.0f / ssum[i];
}

// ---------------- CSR build ----------------
__global__ void k_hist(const int* __restrict__ erow, int* __restrict__ cnt) {
  int t = blockIdx.x * 256 + threadIdx.x;  // t over 2*NE
  int k = t >> 18;
  atomicAdd(cnt + k * NN + erow[t], 1);
}

#define RPS 8208  // rowptr stride per support (padded)
__global__ __launch_bounds__(256) void k_scan(const int* __restrict__ cnt,
                                              int* __restrict__ rowptr,
                                              int* __restrict__ fill) {
  int k = blockIdx.x;
  const int* c = cnt + k * NN;
  int* rp = rowptr + k * RPS;
  int* fl = fill + k * NN;
  __shared__ int part[256];
  int t = threadIdx.x;
  int local[32];
  int s = 0;
#pragma unroll
  for (int i = 0; i < 32; i++) { local[i] = c[t * 32 + i]; s += local[i]; }
  part[t] = s;
  __syncthreads();
  for (int off = 1; off < 256; off <<= 1) {
    int v = (t >= off) ? part[t - off] : 0;
    __syncthreads();
    part[t] += v;
    __syncthreads();
  }
  int run = (t == 0) ? 0 : part[t - 1];
#pragma unroll
  for (int i = 0; i < 32; i++) {
    rp[t * 32 + i] = run;
    fl[t * 32 + i] = run;
    run += local[i];
  }
  if (t == 255) rp[NN] = run;
}

__global__ void k_scatter(const int* __restrict__ erow, const int* __restrict__ ecol,
                          const float* __restrict__ ew, int* __restrict__ fill,
                          int* __restrict__ ecol_s, float* __restrict__ ew_s) {
  int t = blockIdx.x * 256 + threadIdx.x;  // t over 2*NE
  int k = t >> 18;
  int r = erow[t];
  int pos = atomicAdd(fill + k * NN + r, 1);
  ecol_s[(size_t)k * NE + pos] = ecol[t];
  ew_s[(size_t)k * NE + pos] = ew[t];
}

// ---------------- CSR SpMM: one wave per row, no atomics ----------------
__global__ __launch_bounds__(256) void k_csr(const int* __restrict__ rowptr,
                                             const int* __restrict__ cols,
                                             const float* __restrict__ w,
                                             const float* __restrict__ src,
                                             float* __restrict__ dst,
                                             const float* __restrict__ extra,
                                             float scale) {
  int wid = threadIdx.x >> 6;
  int lane = threadIdx.x & 63;
  int row = blockIdx.x * 4 + wid;
  int start = rowptr[row], end = rowptr[row + 1];
  float a0x = 0.f, a0y = 0.f, a0z = 0.f, a0w = 0.f;
  float a1x = 0.f, a1y = 0.f, a1z = 0.f, a1w = 0.f;
  for (int e = start; e < end; e++) {
    int c = __builtin_amdgcn_readfirstlane(cols[e]);
    float wv = w[e];
    const float4* s = (const float4*)(src + (size_t)c * BD);
    float4 v0 = s[lane], v1 = s[lane + 64];
    a0x += wv * v0.x; a0y += wv * v0.y; a0z += wv * v0.z; a0w += wv * v0.w;
    a1x += wv * v1.x; a1y += wv * v1.y; a1z += wv * v1.z; a1w += wv * v1.w;
  }
  float4* d = (float4*)(dst + (size_t)row * BD);
  if (extra) {
    const float4* ex = (const float4*)(extra + (size_t)row * BD);
    float4 e0 = ex[lane], e1 = ex[lane + 64];
    float4 d0 = d[lane], d1 = d[lane + 64];
    d0.x += scale * a0x + e0.x; d0.y += scale * a0y + e0.y;
    d0.z += scale * a0z + e0.z; d0.w += scale * a0w + e0.w;
    d1.x += scale * a1x + e1.x; d1.y += scale * a1y + e1.y;
    d1.z += scale * a1z + e1.z; d1.w += scale * a1w + e1.w;
    d[lane] = d0; d[lane + 64] = d1;
  } else {
    float4 d0 = {a0x, a0y, a0z, a0w};
    float4 d1 = {a1x, a1y, a1z, a1w};
    d[lane] = d0; d[lane + 64] = d1;
  }
}

// ---------------- fused adaptive-adjacency MFMA GEMM ----------------
// Ysum[i, f] += sum_j exp(relu(Z_i.Z_j))*invs[j] * Y0[j, f]
// Block: 32 i x 256 f; wave w: S-frag for j-sub w*32, PV for f-slice w*64.
__global__ __launch_bounds__(256) void k2(const unsigned short* __restrict__ Zh,
                                          const unsigned short* __restrict__ Zl,
                                          const unsigned short* __restrict__ Y0bT,
                                          const float* __restrict__ invs,
                                          float* __restrict__ Ysum) {
  __shared__ unsigned short P[32 * 128];  // XOR-swizzled [i][j] bf16
  int i0 = blockIdx.x * 32;
  int f0 = blockIdx.y * 256;
  int tid = threadIdx.x;
  int w = tid >> 6, lane = tid & 63, li = lane & 31, h = lane >> 5;

  // hoist A = Z[i-tile] fragments (hi/lo, 4 k-steps)
  short8 aih[4], ail[4];
#pragma unroll
  for (int ks = 0; ks < 4; ks++) {
    aih[ks] = *(const short8*)(Zh + (size_t)(i0 + li) * DE + ks * 16 + 8 * h);
    ail[ks] = *(const short8*)(Zl + (size_t)(i0 + li) * DE + ks * 16 + 8 * h);
  }
  float16 acc0, acc1;
#pragma unroll
  for (int r = 0; r < 16; r++) { acc0[r] = 0.f; acc1[r] = 0.f; }

  for (int js = 0; js < 64; js++) {
    int j0 = js * 128;
    int jj = j0 + w * 32 + li;
    short8 bjh[4], bjl[4];
#pragma unroll
    for (int ks = 0; ks < 4; ks++) {
      bjh[ks] = *(const short8*)(Zh + (size_t)jj * DE + ks * 16 + 8 * h);
      bjl[ks] = *(const short8*)(Zl + (size_t)jj * DE + ks * 16 + 8 * h);
    }
    float16 s;
#pragma unroll
    for (int r = 0; r < 16; r++) s[r] = 0.f;
#pragma unroll
    for (int ks = 0; ks < 4; ks++) {
      s = MFMA(aih[ks], bjh[ks], s);   // hi*hi
      s = MFMA(aih[ks], bjl[ks], s);   // hi*lo
      s = MFMA(ail[ks], bjh[ks], s);   // lo*hi
    }
    float iv = invs[jj];
#pragma unroll
    for (int r = 0; r < 16; r++) {
      float pv = __expf(fminf(fmaxf(s[r], 0.f), 80.f)) * iv;
      int il = (r & 3) + 8 * (r >> 2) + 4 * h;
      P[(il * 128 + w * 32 + li) ^ ((il & 7) * 8)] = f2b(pv);
    }
    __syncthreads();
#pragma unroll
    for (int ks2 = 0; ks2 < 8; ks2++) {
      short8 af = *(const short8*)(P + ((li * 128 + ks2 * 16 + 8 * h) ^ ((li & 7) * 8)));
      const unsigned short* bp =
          Y0bT + (size_t)(f0 + w * 64 + li) * NN + j0 + ks2 * 16 + 8 * h;
      short8 bf0 = *(const short8*)bp;
      short8 bf1 = *(const short8*)(bp + (size_t)32 * NN);
      acc0 = MFMA(af, bf0, acc0);
      acc1 = MFMA(af, bf1, acc1);
    }
    __syncthreads();
  }
#pragma unroll
  for (int r = 0; r < 16; r++) {
    int i = i0 + (r & 3) + 8 * (r >> 2) + 4 * h;
    int f = f0 + w * 64 + li;
    Ysum[(size_t)i * BD + f] += acc0[r];
    Ysum[(size_t)i * BD + f + 32] += acc1[r];
  }
}

// ---------------- out[b,n,o] = sum_d Ysum[n, b*32+d] * W[d,o] ----------------
__global__ void k3(const float* __restrict__ Ysum, const float* __restrict__ W,
                   float* __restrict__ out) {
  __shared__ float yt[32][68];  // [d][n]
  __shared__ float wt[32][68];  // [d][o]
  int n0 = blockIdx.x * 64;
  int b = blockIdx.y;
  int tid = threadIdx.x;
#pragma unroll
  for (int q = 0; q < 2; q++) {
    int flat = (q * 256 + tid) * 4;
    int r = flat >> 5, c = flat & 31;
    float4 a = *(const float4*)(Ysum + (size_t)(n0 + r) * BD + b * 32 + c);
    yt[c + 0][r] = a.x; yt[c + 1][r] = a.y; yt[c + 2][r] = a.z; yt[c + 3][r] = a.w;
    int rd = flat >> 6, co = flat & 63;
    *(float4*)&wt[rd][co] = *(const float4*)(W + rd * 64 + co);
  }
  __syncthreads();
  int tx = tid & 15, ty = tid >> 4;
  float acc[4][4];
#pragma unroll
  for (int a = 0; a < 4; a++)
#pragma unroll
    for (int bq = 0; bq < 4; bq++) acc[a][bq] = 0.f;
#pragma unroll
  for (int d = 0; d < 32; d++) {
    float4 a = *(const float4*)&yt[d][ty * 4];
    float4 w4 = *(const float4*)&wt[d][tx * 4];
    float av[4] = {a.x, a.y, a.z, a.w}, wv[4] = {w4.x, w4.y, w4.z, w4.w};
#pragma unroll
    for (int nn = 0; nn < 4; nn++)
#pragma unroll
      for (int oo = 0; oo < 4; oo++) acc[nn][oo] += av[nn] * wv[oo];
  }
#pragma unroll
  for (int nn = 0; nn < 4; nn++) {
    float4 v = {acc[nn][0], acc[nn][1], acc[nn][2], acc[nn][3]};
    *(float4*)(out + (size_t)b * NN * 64 + (size_t)(n0 + ty * 4 + nn) * 64 + tx * 4) = v;
  }
}

extern "C" void kernel_launch(void* const* d_in, const int* in_sizes, int n_in,
                              void* d_out, int out_size, void* d_ws, size_t ws_size,
                              hipStream_t stream) {
  const int* erow = (const int*)d_in[0];
  const int* ecol = (const int*)d_in[1];
  const float* ew = (const float*)d_in[2];
  const float* X = (const float*)d_in[3];
  const float* Z = (const float*)d_in[4];
  const float* W = (const float*)d_in[5];
  float* out = (float*)d_out;

  char* p = (char*)d_ws;
  float* Y0 = (float*)p;            p += (size_t)NN * BD * 4;   // 16 MB
  float* Ysum = (float*)p;          p += (size_t)NN * BD * 4;   // 16 MB
  float* Y1 = (float*)p;            p += (size_t)NN * BD * 4;   // 16 MB
  unsigned short* Y0bT = (unsigned short*)p; p += (size_t)BD * NN * 2;  // 8 MB
  unsigned short* Zh = (unsigned short*)p;   p += (size_t)NN * DE * 2;  // 1 MB
  unsigned short* Zl = (unsigned short*)p;   p += (size_t)NN * DE * 2;  // 1 MB
  float* ssum = (float*)p;          p += NN * 4;
  float* invs = (float*)p;          p += NN * 4;
  int* cnt = (int*)p;               p += 2 * NN * 4;
  int* rowptr = (int*)p;            p += 2 * RPS * 4;
  int* fill = (int*)p;              p += 2 * NN * 4;
  int* ecol_s = (int*)p;            p += (size_t)2 * NE * 4;
  float* ew_s = (float*)p;          p += (size_t)2 * NE * 4;

  k_transpose<<<dim3(NN / 32, BD / 32), dim3(32, 8), 0, stream>>>(X, Y0, Ysum);
  k_cast<<<(NN * BD / 8) / 256, 256, 0, stream>>>(X, Y0bT);
  k_zsplit<<<(NN * DE / 4) / 256, 256, 0, stream>>>(Z, Zh, Zl);
  hipMemsetAsync(ssum, 0, NN * sizeof(float), stream);
  hipMemsetAsync(cnt, 0, 2 * NN * sizeof(int), stream);
  k_hist<<<2 * NE / 256, 256, 0, stream>>>(erow, cnt);
  k_scan<<<2, 256, 0, stream>>>(cnt, rowptr, fill);
  k_scatter<<<2 * NE / 256, 256, 0, stream>>>(erow, ecol, ew, fill, ecol_s, ew_s);
  k_colsum<<<dim3(128, 4), 256, 0, stream>>>(Zh, Zl, ssum);
  k_inv<<<NN / 256, 256, 0, stream>>>(ssum, invs);
  for (int k = 0; k < 2; k++) {
    const int* rp = rowptr + k * RPS;
    const int* cs = ecol_s + (size_t)k * NE;
    const float* ws = ew_s + (size_t)k * NE;
    k_csr<<<NN / 4, 256, 0, stream>>>(rp, cs, ws, Y0, Y1, nullptr, 1.0f);
    k_csr<<<NN / 4, 256, 0, stream>>>(rp, cs, ws, Y1, Ysum, Y1, 2.0f);
  }
  k2<<<dim3(NN / 32, 2), 256, 0, stream>>>(Zh, Zl, Y0bT, invs, Ysum);
  k3<<<dim3(NN / 64, 16), 256, 0, stream>>>(Ysum, W, out);
}